// Round 8
// baseline (419.494 us; speedup 1.0000x reference)
//
#include <hip/hip_runtime.h>
#include <hip/hip_bf16.h>

typedef unsigned short ushort_t;
typedef __attribute__((ext_vector_type(8))) short bf16x8;
typedef __attribute__((ext_vector_type(4))) float f32x4;
typedef __attribute__((ext_vector_type(8))) unsigned short u16x8;
typedef __attribute__((ext_vector_type(4))) unsigned short u16x4;

#define NDIM 2048
#define BDIM 8

__device__ __forceinline__ float bf2f(unsigned short u) {
  union { unsigned int i; float f; } v; v.i = ((unsigned int)u) << 16; return v.f;
}
__device__ __forceinline__ unsigned short f2bf(float f) {
  union { float f; unsigned int i; } v; v.f = f;
  unsigned int x = v.i;
  x += 0x7fffu + ((x >> 16) & 1u);   // round to nearest even
  return (unsigned short)(x >> 16);
}

__device__ __forceinline__ void gload16(const void* g, void* l) {
  __builtin_amdgcn_global_load_lds(
      (const __attribute__((address_space(1))) void*)g,
      (__attribute__((address_space(3))) void*)l,
      16, 0, 0);
}

// ---------- elementwise f32 -> bf16 ----------
__global__ __launch_bounds__(256) void convert_bf16(const float* __restrict__ src,
                                                    unsigned short* __restrict__ dst, int n) {
  int i = (blockIdx.x * 256 + threadIdx.x) * 4;
  if (i < n) {
    f32x4 v = *(const f32x4*)&src[i];
    u16x4 w;
    #pragma unroll
    for (int k = 0; k < 4; ++k) w[k] = f2bf(v[k]);
    *(u16x4*)&dst[i] = w;
  }
}

// ---------- x [b][c][n] f32 -> cur_T [b][n][c] bf16 ----------
__global__ __launch_bounds__(256) void transpose_convert(const float* __restrict__ x,
                                                         unsigned short* __restrict__ dst) {
  __shared__ float tile[64][65];
  const int b  = blockIdx.z;
  const int n0 = blockIdx.x * 64;
  const int c0 = blockIdx.y * 64;
  const int tr = threadIdx.x >> 4;   // 0..15
  const int tc = threadIdx.x & 15;   // 0..15
  const float* src = x + ((size_t)b * NDIM + c0) * NDIM + n0;
  #pragma unroll
  for (int p = 0; p < 4; ++p) {
    int r = p * 16 + tr;
    f32x4 v = *(const f32x4*)&src[(size_t)r * NDIM + tc * 4];
    #pragma unroll
    for (int k = 0; k < 4; ++k) tile[r][tc * 4 + k] = v[k];
  }
  __syncthreads();
  unsigned short* d = dst + ((size_t)b * NDIM + n0) * NDIM + c0;
  #pragma unroll
  for (int p = 0; p < 4; ++p) {
    int r = p * 16 + tr;   // n-local
    u16x4 w;
    #pragma unroll
    for (int k = 0; k < 4; ++k) w[k] = f2bf(tile[tc * 4 + k][r]);
    *(u16x4*)&d[(size_t)r * NDIM + tc * 4] = w;
  }
}

// ---------- wbeff = Wa^T Wb, wceff = Wa^T Wc (two-stage, no atomics) ----------
__global__ __launch_bounds__(256) void weff1(const float* __restrict__ Wa,
                                             const float* __restrict__ Wb,
                                             const float* __restrict__ Wc,
                                             float* __restrict__ part) {
  int c  = blockIdx.x * 256 + threadIdx.x;
  int o0 = blockIdx.y * 128;
  float ab = 0.f, ac = 0.f;
  for (int o = o0; o < o0 + 128; ++o) {
    float w = Wa[(size_t)o * NDIM + c];
    ab = fmaf(Wb[o], w, ab);
    ac = fmaf(Wc[o], w, ac);
  }
  part[(size_t)(blockIdx.y * 2 + 0) * NDIM + c] = ab;
  part[(size_t)(blockIdx.y * 2 + 1) * NDIM + c] = ac;
}
__global__ __launch_bounds__(256) void weff2(const float* __restrict__ part,
                                             float* __restrict__ wbe, float* __restrict__ wce) {
  int c = blockIdx.x * 256 + threadIdx.x;
  float ab = 0.f, ac = 0.f;
  #pragma unroll
  for (int i = 0; i < 16; ++i) {
    ab += part[(size_t)(i * 2 + 0) * NDIM + c];
    ac += part[(size_t)(i * 2 + 1) * NDIM + c];
  }
  wbe[c] = ab; wce[c] = ac;
}

// ---------- t1[b,n] = wbeff . cur_T[b,n,:] + bb ; t2 likewise ----------
__global__ __launch_bounds__(256) void t_kernel(const unsigned short* __restrict__ curT,
                                                const float* __restrict__ wbe,
                                                const float* __restrict__ wce,
                                                const float* __restrict__ bb,
                                                const float* __restrict__ bc,
                                                float* __restrict__ t1, float* __restrict__ t2) {
  int row  = blockIdx.x * 4 + (threadIdx.x >> 6);  // (b,n) flat, one wave per row
  int lane = threadIdx.x & 63;
  const unsigned short* r = curT + (size_t)row * NDIM;
  float a1 = 0.f, a2 = 0.f;
  #pragma unroll
  for (int p = 0; p < 4; ++p) {
    int c0 = p * 512 + lane * 8;
    u16x8 v = *(const u16x8*)&r[c0];
    f32x4 w1a = *(const f32x4*)&wbe[c0];
    f32x4 w1b = *(const f32x4*)&wbe[c0 + 4];
    f32x4 w2a = *(const f32x4*)&wce[c0];
    f32x4 w2b = *(const f32x4*)&wce[c0 + 4];
    #pragma unroll
    for (int j = 0; j < 4; ++j) {
      float xv = bf2f(v[j]);
      a1 = fmaf(w1a[j], xv, a1);
      a2 = fmaf(w2a[j], xv, a2);
    }
    #pragma unroll
    for (int j = 0; j < 4; ++j) {
      float xv = bf2f(v[4 + j]);
      a1 = fmaf(w1b[j], xv, a1);
      a2 = fmaf(w2b[j], xv, a2);
    }
  }
  #pragma unroll
  for (int off = 32; off > 0; off >>= 1) {
    a1 += __shfl_xor(a1, off);
    a2 += __shfl_xor(a2, off);
  }
  if (lane == 0) { t1[row] = a1 + bb[0]; t2[row] = a2 + bc[0]; }
}

// ---------- S[o,n] = log sum_b exp(lrelu(t1[b,n]+t2[b,o])) ----------
__global__ __launch_bounds__(256) void s_kernel(const float* __restrict__ t1,
                                                const float* __restrict__ t2,
                                                float* __restrict__ S) {
  int n = blockIdx.x * 256 + threadIdx.x;
  int o = blockIdx.y;
  float acc = 0.f;
  #pragma unroll
  for (int b = 0; b < BDIM; ++b) {
    float z = t1[b * NDIM + n] + t2[b * NDIM + o];
    z = z >= 0.f ? z : 0.2f * z;
    acc += __expf(z);
  }
  S[(size_t)o * NDIM + n] = __logf(acc);
}

// ---------- fused GEMM + softmax-scale epilogue ----------
// 256(M)x128(N) tile, BK=32, 8 waves (4M x 2N, 64x64 each), ring-3 LDS
// (72 KiB -> 2 blocks/CU, 4 waves/SIMD). Cross-block anti-phase gives the
// MFMA<->LDS overlap that a single barrier-locked block cannot. One barrier
// per window, counted vmcnt(3): tile t+1 landed, t+2 in flight.
__global__ __launch_bounds__(512, 4) void gemm_fused(
    const unsigned short* __restrict__ A,    // Wa bf16 [2048][2048], k-contig
    const unsigned short* __restrict__ Bt,   // cur_T bf16 [8][2048][2048], k-contig
    const float* __restrict__ t1, const float* __restrict__ t2,
    const float* __restrict__ S,  const float* __restrict__ bias,
    unsigned short* __restrict__ outT,       // next cur_T (step 0)
    float* __restrict__ outF,                // d_out (step 1)
    int write_f32) {
  // ring of 3 buffers; each: A-tile 256x32 (16KB, 8192 ushort) + B 128x32 (8KB)
  __shared__ __align__(16) unsigned short sbuf[3 * 12288];  // 72 KiB

  const int tid  = threadIdx.x;
  const int lane = tid & 63;
  const int w    = tid >> 6;           // wave 0..7
  const int wr   = w >> 1;             // 0..3  (M)
  const int wc   = w & 1;              // 0..1  (N)
  const int bn0  = blockIdx.x * 128;
  const int bm0  = blockIdx.y * 256;
  const int bz   = blockIdx.z;
  const unsigned short* Bb = Bt + (size_t)bz * NDIM * NDIM;

  f32x4 acc[4][4];
  #pragma unroll
  for (int m = 0; m < 4; ++m)
    #pragma unroll
    for (int n = 0; n < 4; ++n) acc[m][n] = (f32x4){0.f, 0.f, 0.f, 0.f};

  // ---- staging decode: wave writes LDS linearly (wave base + lane*16B).
  // LDS row r (64B) slot s' is written by lane (r%16)*4 + s', which loads
  // global slot s'^((sr>>1)&3) (row bases are multiples of 16 -> uniform).
  const int sr = lane >> 2;            // row within 16-row chunk
  const int sc = lane & 3;             // 16B slot
  const int sg = sc ^ ((sr >> 1) & 3);
  const unsigned short* a0 = A  + (size_t)(bm0 + (w * 2 + 0) * 16 + sr) * NDIM + sg * 8;
  const unsigned short* a1 = A  + (size_t)(bm0 + (w * 2 + 1) * 16 + sr) * NDIM + sg * 8;
  const unsigned short* b0 = Bb + (size_t)(bn0 + w * 16 + sr) * NDIM + sg * 8;

  auto stage = [&](int kt, int buf) {    // 3 loads: A (2) + B (1)
    gload16(a0 + kt, &sbuf[buf * 12288 + (w * 2 + 0) * 512]);
    gload16(a1 + kt, &sbuf[buf * 12288 + (w * 2 + 1) * 512]);
    gload16(b0 + kt, &sbuf[buf * 12288 + 8192 + w * 512]);
  };

  // ---- fragment-read decode (swizzled): slot' = fs ^ ((fr>>1)&3)
  const int fr = lane & 15;            // fragment row
  const int fs = lane >> 4;            // k-slot 0..3
  const int sp = (fs ^ ((fr >> 1) & 3)) * 8;   // ushort offset within row

  // ---- prologue: stage tiles 0,1 ----
  stage(0, 0);
  stage(32, 1);
  asm volatile("s_waitcnt vmcnt(3)" ::: "memory");   // tile 0 landed
  __builtin_amdgcn_s_barrier();

  // ---- main loop: windows 0..62 (ring-3), tail window 63 ----
  for (int t3 = 0; t3 < 63; t3 += 3) {
    #pragma unroll
    for (int u = 0; u < 3; ++u) {
      const int t  = t3 + u;
      const int cb = u;                          // t % 3
      const int nb = (u + 2) % 3;                // (t+2) % 3
      const int tc = (t + 2 > 63) ? 63 : (t + 2);
      const unsigned short* Ab = &sbuf[cb * 12288];
      const unsigned short* Bl = &sbuf[cb * 12288 + 8192];

      bf16x8 av[4], bv[4];
      #pragma unroll
      for (int m = 0; m < 4; ++m)
        av[m] = *(const bf16x8*)&Ab[(wr * 64 + m * 16 + fr) * 32 + sp];
      #pragma unroll
      for (int n = 0; n < 4; ++n)
        bv[n] = *(const bf16x8*)&Bl[(wc * 64 + n * 16 + fr) * 32 + sp];
      stage(tc * 32, nb);
      __builtin_amdgcn_sched_barrier(0);
      asm volatile("s_waitcnt lgkmcnt(0)" ::: "memory");
      __builtin_amdgcn_sched_barrier(0);       // rule #18
      __builtin_amdgcn_s_setprio(1);
      #pragma unroll
      for (int m = 0; m < 4; ++m)
        #pragma unroll
        for (int n = 0; n < 4; ++n)
          acc[m][n] = __builtin_amdgcn_mfma_f32_16x16x32_bf16(av[m], bv[n], acc[m][n], 0, 0, 0);
      __builtin_amdgcn_s_setprio(0);
      __builtin_amdgcn_sched_barrier(0);
      // counted wait: only tile t+2's 3 loads remain; tile t+1 landed
      asm volatile("s_waitcnt vmcnt(3)" ::: "memory");
      __builtin_amdgcn_s_barrier();
    }
  }
  {  // ---- tail window t=63 (buf 0, no staging) ----
    const unsigned short* Ab = &sbuf[0];
    const unsigned short* Bl = &sbuf[8192];
    bf16x8 av[4], bv[4];
    #pragma unroll
    for (int m = 0; m < 4; ++m)
      av[m] = *(const bf16x8*)&Ab[(wr * 64 + m * 16 + fr) * 32 + sp];
    #pragma unroll
    for (int n = 0; n < 4; ++n)
      bv[n] = *(const bf16x8*)&Bl[(wc * 64 + n * 16 + fr) * 32 + sp];
    asm volatile("s_waitcnt lgkmcnt(0)" ::: "memory");
    __builtin_amdgcn_sched_barrier(0);
    #pragma unroll
    for (int m = 0; m < 4; ++m)
      #pragma unroll
      for (int n = 0; n < 4; ++n)
        acc[m][n] = __builtin_amdgcn_mfma_f32_16x16x32_bf16(av[m], bv[n], acc[m][n], 0, 0, 0);
  }

  // ---- epilogue ----
  __syncthreads();                       // all reads of sbuf done before reuse
  float* sT1f = (float*)&sbuf[0];        // 128 floats
  float* sT2f = sT1f + 128;              // 256 floats
  if (tid < 128) sT1f[tid] = t1[bz * NDIM + bn0 + tid];
  else if (tid < 384) sT2f[tid - 128] = t2[bz * NDIM + bm0 + (tid - 128)];
  __syncthreads();

  const int lr4 = fs * 4;
  #pragma unroll
  for (int m = 0; m < 4; ++m) {
    #pragma unroll
    for (int n = 0; n < 4; ++n) {
      const int oo = wr * 64 + m * 16 + lr4;    // local o of 4 consecutive rows
      const int nn = wc * 64 + n * 16 + fr;     // local n
      const int o  = bm0 + oo;
      const int ng = bn0 + nn;
      const float tz1  = sT1f[nn];
      const float bval = bias[ng];
      if (write_f32) {
        #pragma unroll
        for (int r = 0; r < 4; ++r) {
          float z = tz1 + sT2f[oo + r];
          z = z >= 0.f ? z : 0.2f * z;
          float coef = __expf(z - S[(size_t)(o + r) * NDIM + ng]);
          outF[(size_t)bz * NDIM * NDIM + (size_t)(o + r) * NDIM + ng] =
              fmaf(coef, acc[m][n][r], bval);
        }
      } else {
        u16x4 wv;
        #pragma unroll
        for (int r = 0; r < 4; ++r) {
          float z = tz1 + sT2f[oo + r];
          z = z >= 0.f ? z : 0.2f * z;
          float coef = __expf(z - S[(size_t)(o + r) * NDIM + ng]);
          wv[r] = f2bf(fmaf(coef, acc[m][n][r], bval));
        }
        *(u16x4*)&outT[(size_t)bz * NDIM * NDIM + (size_t)ng * NDIM + o] = wv;
      }
    }
  }
}

extern "C" void kernel_launch(void* const* d_in, const int* in_sizes, int n_in,
                              void* d_out, int out_size, void* d_ws, size_t ws_size,
                              hipStream_t stream) {
  const float* x    = (const float*)d_in[0];
  const float* Wa   = (const float*)d_in[1];
  const float* Wb   = (const float*)d_in[2];
  const float* bb   = (const float*)d_in[3];
  const float* Wc   = (const float*)d_in[4];
  const float* bc   = (const float*)d_in[5];
  const float* bias = (const float*)d_in[6];
  float* out = (float*)d_out;

  char* ws = (char*)d_ws;
  unsigned short* curA = (unsigned short*)ws; ws += (size_t)BDIM * NDIM * NDIM * 2;
  unsigned short* curB = (unsigned short*)ws; ws += (size_t)BDIM * NDIM * NDIM * 2;
  unsigned short* WaB  = (unsigned short*)ws; ws += (size_t)NDIM * NDIM * 2;
  float* t1   = (float*)ws; ws += (size_t)BDIM * NDIM * 4;
  float* t2   = (float*)ws; ws += (size_t)BDIM * NDIM * 4;
  float* wbe  = (float*)ws; ws += NDIM * 4;
  float* wce  = (float*)ws; ws += NDIM * 4;
  float* part = (float*)ws; ws += (size_t)32 * NDIM * 4;
  float* S    = (float*)ws; ws += (size_t)NDIM * NDIM * 4;

  convert_bf16<<<4096, 256, 0, stream>>>(Wa, WaB, NDIM * NDIM);
  transpose_convert<<<dim3(32, 32, BDIM), 256, 0, stream>>>(x, curA);
  weff1<<<dim3(8, 16), 256, 0, stream>>>(Wa, Wb, Wc, part);
  weff2<<<8, 256, 0, stream>>>(part, wbe, wce);

  for (int step = 0; step < 2; ++step) {
    const unsigned short* cur = step ? curB : curA;
    t_kernel<<<(BDIM * NDIM) / 4, 256, 0, stream>>>(cur, wbe, wce, bb, bc, t1, t2);
    s_kernel<<<dim3(NDIM / 256, NDIM), 256, 0, stream>>>(t1, t2, S);
    gemm_fused<<<dim3(16, 8, BDIM), 512, 0, stream>>>(
        WaB, cur, t1, t2, S, bias, curB, out, step);
  }
}

// Round 9
// 374.925 us; speedup vs baseline: 1.1189x; 1.1189x over previous
//
#include <hip/hip_runtime.h>
#include <hip/hip_bf16.h>

typedef unsigned short ushort_t;
typedef __attribute__((ext_vector_type(8))) short bf16x8;
typedef __attribute__((ext_vector_type(4))) float f32x4;
typedef __attribute__((ext_vector_type(8))) unsigned short u16x8;
typedef __attribute__((ext_vector_type(4))) unsigned short u16x4;

#define NDIM 2048
#define BDIM 8

__device__ __forceinline__ float bf2f(unsigned short u) {
  union { unsigned int i; float f; } v; v.i = ((unsigned int)u) << 16; return v.f;
}
__device__ __forceinline__ unsigned short f2bf(float f) {
  union { float f; unsigned int i; } v; v.f = f;
  unsigned int x = v.i;
  x += 0x7fffu + ((x >> 16) & 1u);   // round to nearest even
  return (unsigned short)(x >> 16);
}

__device__ __forceinline__ void gload16(const void* g, void* l) {
  __builtin_amdgcn_global_load_lds(
      (const __attribute__((address_space(1))) void*)g,
      (__attribute__((address_space(3))) void*)l,
      16, 0, 0);
}

// ---------- elementwise f32 -> bf16 ----------
__global__ __launch_bounds__(256) void convert_bf16(const float* __restrict__ src,
                                                    unsigned short* __restrict__ dst, int n) {
  int i = (blockIdx.x * 256 + threadIdx.x) * 4;
  if (i < n) {
    f32x4 v = *(const f32x4*)&src[i];
    u16x4 w;
    #pragma unroll
    for (int k = 0; k < 4; ++k) w[k] = f2bf(v[k]);
    *(u16x4*)&dst[i] = w;
  }
}

// ---------- x [b][c][n] f32 -> cur_T [b][n][c] bf16 ----------
__global__ __launch_bounds__(256) void transpose_convert(const float* __restrict__ x,
                                                         unsigned short* __restrict__ dst) {
  __shared__ float tile[64][65];
  const int b  = blockIdx.z;
  const int n0 = blockIdx.x * 64;
  const int c0 = blockIdx.y * 64;
  const int tr = threadIdx.x >> 4;   // 0..15
  const int tc = threadIdx.x & 15;   // 0..15
  const float* src = x + ((size_t)b * NDIM + c0) * NDIM + n0;
  #pragma unroll
  for (int p = 0; p < 4; ++p) {
    int r = p * 16 + tr;
    f32x4 v = *(const f32x4*)&src[(size_t)r * NDIM + tc * 4];
    #pragma unroll
    for (int k = 0; k < 4; ++k) tile[r][tc * 4 + k] = v[k];
  }
  __syncthreads();
  unsigned short* d = dst + ((size_t)b * NDIM + n0) * NDIM + c0;
  #pragma unroll
  for (int p = 0; p < 4; ++p) {
    int r = p * 16 + tr;   // n-local
    u16x4 w;
    #pragma unroll
    for (int k = 0; k < 4; ++k) w[k] = f2bf(tile[tc * 4 + k][r]);
    *(u16x4*)&d[(size_t)r * NDIM + tc * 4] = w;
  }
}

// ---------- wbeff = Wa^T Wb, wceff = Wa^T Wc (two-stage, no atomics) ----------
__global__ __launch_bounds__(256) void weff1(const float* __restrict__ Wa,
                                             const float* __restrict__ Wb,
                                             const float* __restrict__ Wc,
                                             float* __restrict__ part) {
  int c  = blockIdx.x * 256 + threadIdx.x;
  int o0 = blockIdx.y * 128;
  float ab = 0.f, ac = 0.f;
  for (int o = o0; o < o0 + 128; ++o) {
    float w = Wa[(size_t)o * NDIM + c];
    ab = fmaf(Wb[o], w, ab);
    ac = fmaf(Wc[o], w, ac);
  }
  part[(size_t)(blockIdx.y * 2 + 0) * NDIM + c] = ab;
  part[(size_t)(blockIdx.y * 2 + 1) * NDIM + c] = ac;
}
__global__ __launch_bounds__(256) void weff2(const float* __restrict__ part,
                                             float* __restrict__ wbe, float* __restrict__ wce) {
  int c = blockIdx.x * 256 + threadIdx.x;
  float ab = 0.f, ac = 0.f;
  #pragma unroll
  for (int i = 0; i < 16; ++i) {
    ab += part[(size_t)(i * 2 + 0) * NDIM + c];
    ac += part[(size_t)(i * 2 + 1) * NDIM + c];
  }
  wbe[c] = ab; wce[c] = ac;
}

// ---------- t1[b,n] = wbeff . cur_T[b,n,:] + bb ; t2 likewise ----------
__global__ __launch_bounds__(256) void t_kernel(const unsigned short* __restrict__ curT,
                                                const float* __restrict__ wbe,
                                                const float* __restrict__ wce,
                                                const float* __restrict__ bb,
                                                const float* __restrict__ bc,
                                                float* __restrict__ t1, float* __restrict__ t2) {
  int row  = blockIdx.x * 4 + (threadIdx.x >> 6);  // (b,n) flat, one wave per row
  int lane = threadIdx.x & 63;
  const unsigned short* r = curT + (size_t)row * NDIM;
  float a1 = 0.f, a2 = 0.f;
  #pragma unroll
  for (int p = 0; p < 4; ++p) {
    int c0 = p * 512 + lane * 8;
    u16x8 v = *(const u16x8*)&r[c0];
    f32x4 w1a = *(const f32x4*)&wbe[c0];
    f32x4 w1b = *(const f32x4*)&wbe[c0 + 4];
    f32x4 w2a = *(const f32x4*)&wce[c0];
    f32x4 w2b = *(const f32x4*)&wce[c0 + 4];
    #pragma unroll
    for (int j = 0; j < 4; ++j) {
      float xv = bf2f(v[j]);
      a1 = fmaf(w1a[j], xv, a1);
      a2 = fmaf(w2a[j], xv, a2);
    }
    #pragma unroll
    for (int j = 0; j < 4; ++j) {
      float xv = bf2f(v[4 + j]);
      a1 = fmaf(w1b[j], xv, a1);
      a2 = fmaf(w2b[j], xv, a2);
    }
  }
  #pragma unroll
  for (int off = 32; off > 0; off >>= 1) {
    a1 += __shfl_xor(a1, off);
    a2 += __shfl_xor(a2, off);
  }
  if (lane == 0) { t1[row] = a1 + bb[0]; t2[row] = a2 + bc[0]; }
}

// ---------- S[o,n] = log sum_b exp(lrelu(t1[b,n]+t2[b,o])) ----------
__global__ __launch_bounds__(256) void s_kernel(const float* __restrict__ t1,
                                                const float* __restrict__ t2,
                                                float* __restrict__ S) {
  int n = blockIdx.x * 256 + threadIdx.x;
  int o = blockIdx.y;
  float acc = 0.f;
  #pragma unroll
  for (int b = 0; b < BDIM; ++b) {
    float z = t1[b * NDIM + n] + t2[b * NDIM + o];
    z = z >= 0.f ? z : 0.2f * z;
    acc += __expf(z);
  }
  S[(size_t)o * NDIM + n] = __logf(acc);
}

// ---------- fused GEMM + softmax-scale epilogue (m201 8-phase port) ----------
// BM=BN=256, BK=64, 8 waves (2M x 4N), LDS dbuf-2 (128 KiB).
// Iteration = 2 K-tiles = 8 phases. Each phase: {ds_reads (12/4/8/0, frag
// reuse across quadrants) ; ONE half-tile stage (2 gloads) ; barrier ;
// lgkmcnt(0) ; 16 MFMA (one C-quadrant x K=64) ; [vmcnt(6) @ P4/P8] ; barrier}.
// Stage-half row sets == rows freed exactly one phase earlier (hazard-audited).
__global__ __launch_bounds__(512, 2) void gemm_fused(
    const unsigned short* __restrict__ A,    // Wa bf16 [2048][2048], k-contig
    const unsigned short* __restrict__ Bt,   // cur_T bf16 [8][2048][2048], k-contig
    const float* __restrict__ t1, const float* __restrict__ t2,
    const float* __restrict__ S,  const float* __restrict__ bias,
    unsigned short* __restrict__ outT,       // next cur_T (step 0)
    float* __restrict__ outF,                // d_out (step 1)
    int write_f32) {
  // [d][ A 256x64 (16384 us) | B 256x64 (16384 us) ]
  __shared__ __align__(16) unsigned short sbuf[65536];  // 128 KiB

  const int tid  = threadIdx.x;
  const int lane = tid & 63;
  const int w    = tid >> 6;           // wave 0..7
  const int wr   = w >> 2;             // 0..1  (M)
  const int wc   = w & 3;              // 0..3  (N)
  const int bn0  = blockIdx.x * 256;   // x fastest -> one bn panel per XCD
  const int bm0  = blockIdx.y * 256;
  const int bz   = blockIdx.z;
  const unsigned short* Bb = Bt + (size_t)bz * NDIM * NDIM;

  f32x4 acc[8][4];
  #pragma unroll
  for (int m = 0; m < 8; ++m)
    #pragma unroll
    for (int n = 0; n < 4; ++n) acc[m][n] = (f32x4){0.f, 0.f, 0.f, 0.f};

  // ---- staging decode. Rows are 128B; DMA writes linear (lane*16B).
  // Linear slot' s'=lane&7 at row_l=base+(lane>>3) must hold global k-slot
  // s = s' ^ (row_l & 7)  (XOR swizzle, involution; bases are mult. of 8).
  const int sst   = (lane & 7) ^ (lane >> 3);
  const int srowl = lane >> 3;
  const int kk0 = w * 2, kk1 = w * 2 + 1;
  // A-half row map: union over waves of each wr-group's m-half rows
  const int rA0 = (kk0 >> 3) * 128 + (kk0 & 7) * 8;
  const int rA1 = (kk1 >> 3) * 128 + (kk1 & 7) * 8;
  // B-half row map: union of each wc-group's n-half rows
  const int rB0 = (kk0 >> 2) * 64 + (kk0 & 3) * 8;
  const int rB1 = (kk1 >> 2) * 64 + (kk1 & 3) * 8;
  const unsigned short* aG0 = A  + (size_t)(bm0 + rA0 + srowl) * NDIM + sst * 8;
  const unsigned short* aG1 = A  + (size_t)(bm0 + rA1 + srowl) * NDIM + sst * 8;
  const unsigned short* bG0 = Bb + (size_t)(bn0 + rB0 + srowl) * NDIM + sst * 8;
  const unsigned short* bG1 = Bb + (size_t)(bn0 + rB1 + srowl) * NDIM + sst * 8;
  const int aL0 = rA0 * 64, aL1 = rA1 * 64;
  const int bL0 = 16384 + rB0 * 64, bL1 = 16384 + rB1 * 64;

  auto stA = [&](int T, int h, int d) {   // A half-tile: 2 gloads
    gload16(aG0 + (size_t)h * 64 * NDIM + T * 64, &sbuf[d * 32768 + aL0 + h * 4096]);
    gload16(aG1 + (size_t)h * 64 * NDIM + T * 64, &sbuf[d * 32768 + aL1 + h * 4096]);
  };
  auto stB = [&](int T, int h, int d) {
    gload16(bG0 + (size_t)h * 32 * NDIM + T * 64, &sbuf[d * 32768 + bL0 + h * 2048]);
    gload16(bG1 + (size_t)h * 32 * NDIM + T * 64, &sbuf[d * 32768 + bL1 + h * 2048]);
  };

  // ---- fragment decode: row = (group)+fr, slot = (ks*4+fs) ^ (fr&7)
  const int fr = lane & 15;
  const int fs = lane >> 4;
  const int sl0 = ((fs) ^ (fr & 7)) * 8;
  const int sl1 = ((4 + fs) ^ (fr & 7)) * 8;
  const int aOff = (wr * 128 + fr) * 64;
  const int bOff = 16384 + (wc * 64 + fr) * 64;

  bf16x8 a0[4][2], a1f[4][2], b0[2][2], b1[2][2];

  auto rdA = [&](bf16x8 (&dst)[4][2], int d, int mh) {
    const int base = d * 32768 + aOff + mh * 4096;
    #pragma unroll
    for (int m = 0; m < 4; ++m) {
      dst[m][0] = *(const bf16x8*)&sbuf[base + m * 1024 + sl0];
      dst[m][1] = *(const bf16x8*)&sbuf[base + m * 1024 + sl1];
    }
  };
  auto rdB = [&](bf16x8 (&dst)[2][2], int d, int nh) {
    const int base = d * 32768 + bOff + nh * 2048;
    #pragma unroll
    for (int n = 0; n < 2; ++n) {
      dst[n][0] = *(const bf16x8*)&sbuf[base + n * 1024 + sl0];
      dst[n][1] = *(const bf16x8*)&sbuf[base + n * 1024 + sl1];
    }
  };

  auto quad = [&](bf16x8 (&af)[4][2], bf16x8 (&bf)[2][2], int mo, int no) {
    #pragma unroll
    for (int m = 0; m < 4; ++m)
      #pragma unroll
      for (int n = 0; n < 2; ++n)
        #pragma unroll
        for (int ks = 0; ks < 2; ++ks)
          acc[mo + m][no + n] =
              __builtin_amdgcn_mfma_f32_16x16x32_bf16(af[m][ks], bf[n][ks], acc[mo + m][no + n], 0, 0, 0);
  };

  auto phase_open = [&]() {
    __builtin_amdgcn_sched_barrier(0);
    __builtin_amdgcn_s_barrier();
    asm volatile("s_waitcnt lgkmcnt(0)" ::: "memory");
    __builtin_amdgcn_sched_barrier(0);       // rule #18
    __builtin_amdgcn_s_setprio(1);
  };
  auto phase_close = [&](bool vm) {
    __builtin_amdgcn_s_setprio(0);
    __builtin_amdgcn_sched_barrier(0);
    if (vm) asm volatile("s_waitcnt vmcnt(6)" ::: "memory");
    __builtin_amdgcn_s_barrier();
  };

  // ---- prologue: tile0 (4 halves) -> buf0, tile1 (3 halves) -> buf1.
  // vmcnt(6) keeps buf1's 3 pairs in flight; buf0 fully landed.
  stA(0, 0, 0); stB(0, 0, 0); stB(0, 1, 0); stA(0, 1, 0);
  stA(1, 0, 1); stB(1, 0, 1); stB(1, 1, 1);
  asm volatile("s_waitcnt vmcnt(6)" ::: "memory");
  __builtin_amdgcn_s_barrier();

  // ---- main loop: 16 iterations x (2 K-tiles = 8 phases) ----
  #pragma clang loop unroll(disable)
  for (int it = 0; it < 16; ++it) {
    const int T1 = 2 * it + 1;                       // finish staging tile 2it+1
    const int T2 = (it < 15) ? 2 * it + 2 : 31;      // tile -> buf0 (clamped tail)
    const int T3 = (it < 14) ? 2 * it + 3 : 31;      // tile -> buf1

    // ===== K-tile 2it (buf0) =====
    // P1: reads A-mh0 + B-nh0 (12); stage A(T1)h1 -> buf1 (rows read prev P7)
    rdA(a0, 0, 0); rdB(b0, 0, 0); stA(T1, 1, 1);
    phase_open(); quad(a0, b0, 0, 0); phase_close(false);
    // P2: reads B-nh1 (4); stage A(T2)h0 -> buf0 (rows freed at P1)
    rdB(b1, 0, 1); stA(T2, 0, 0);
    phase_open(); quad(a0, b1, 0, 2); phase_close(false);
    // P3: reads A-mh1 (8); stage B(T2)h0 (rows freed at P1)
    rdA(a1f, 0, 1); stB(T2, 0, 0);
    phase_open(); quad(a1f, b0, 4, 0); phase_close(false);
    // P4: pure MFMA; stage B(T2)h1 (rows freed at P2); vmcnt(6)
    stB(T2, 1, 0);
    phase_open(); quad(a1f, b1, 4, 2); phase_close(true);

    // ===== K-tile 2it+1 (buf1) =====
    // P5: reads buf1 A-mh0 + B-nh0; stage A(T2)h1 -> buf0 (rows freed at P3)
    rdA(a0, 1, 0); rdB(b0, 1, 0); stA(T2, 1, 0);
    phase_open(); quad(a0, b0, 0, 0); phase_close(false);
    // P6: reads B-nh1; stage A(T3)h0 -> buf1 (rows freed at P5)
    rdB(b1, 1, 1); stA(T3, 0, 1);
    phase_open(); quad(a0, b1, 0, 2); phase_close(false);
    // P7: reads A-mh1; stage B(T3)h0 (rows freed at P5)
    rdA(a1f, 1, 1); stB(T3, 0, 1);
    phase_open(); quad(a1f, b0, 4, 0); phase_close(false);
    // P8: pure MFMA; stage B(T3)h1 (rows freed at P6); vmcnt(6)
    stB(T3, 1, 1);
    phase_open(); quad(a1f, b1, 4, 2); phase_close(true);
  }

  // drain outstanding DMA before repurposing LDS
  asm volatile("s_waitcnt vmcnt(0)" ::: "memory");
  __syncthreads();

  // ---- epilogue ----
  float* sT1f = (float*)&sbuf[0];
  float* sT2f = sT1f + 256;
  if (tid < 256) sT1f[tid] = t1[bz * NDIM + bn0 + tid];
  else           sT2f[tid - 256] = t2[bz * NDIM + bm0 + (tid - 256)];
  __syncthreads();

  const int lr4 = fs * 4;
  #pragma unroll
  for (int m = 0; m < 8; ++m) {
    #pragma unroll
    for (int n = 0; n < 4; ++n) {
      const int oo = wr * 128 + m * 16 + lr4;   // local o of 4 consecutive rows
      const int nn = wc * 64 + n * 16 + fr;     // local n
      const int o  = bm0 + oo;
      const int ng = bn0 + nn;
      const float tz1  = sT1f[nn];
      const float bval = bias[ng];
      if (write_f32) {
        #pragma unroll
        for (int r = 0; r < 4; ++r) {
          float z = tz1 + sT2f[oo + r];
          z = z >= 0.f ? z : 0.2f * z;
          float coef = __expf(z - S[(size_t)(o + r) * NDIM + ng]);
          outF[(size_t)bz * NDIM * NDIM + (size_t)(o + r) * NDIM + ng] =
              fmaf(coef, acc[m][n][r], bval);
        }
      } else {
        u16x4 wv;
        #pragma unroll
        for (int r = 0; r < 4; ++r) {
          float z = tz1 + sT2f[oo + r];
          z = z >= 0.f ? z : 0.2f * z;
          float coef = __expf(z - S[(size_t)(o + r) * NDIM + ng]);
          wv[r] = f2bf(fmaf(coef, acc[m][n][r], bval));
        }
        *(u16x4*)&outT[(size_t)bz * NDIM * NDIM + (size_t)ng * NDIM + o] = wv;
      }
    }
  }
}

extern "C" void kernel_launch(void* const* d_in, const int* in_sizes, int n_in,
                              void* d_out, int out_size, void* d_ws, size_t ws_size,
                              hipStream_t stream) {
  const float* x    = (const float*)d_in[0];
  const float* Wa   = (const float*)d_in[1];
  const float* Wb   = (const float*)d_in[2];
  const float* bb   = (const float*)d_in[3];
  const float* Wc   = (const float*)d_in[4];
  const float* bc   = (const float*)d_in[5];
  const float* bias = (const float*)d_in[6];
  float* out = (float*)d_out;

  char* ws = (char*)d_ws;
  unsigned short* curA = (unsigned short*)ws; ws += (size_t)BDIM * NDIM * NDIM * 2;
  unsigned short* curB = (unsigned short*)ws; ws += (size_t)BDIM * NDIM * NDIM * 2;
  unsigned short* WaB  = (unsigned short*)ws; ws += (size_t)NDIM * NDIM * 2;
  float* t1   = (float*)ws; ws += (size_t)BDIM * NDIM * 4;
  float* t2   = (float*)ws; ws += (size_t)BDIM * NDIM * 4;
  float* wbe  = (float*)ws; ws += NDIM * 4;
  float* wce  = (float*)ws; ws += NDIM * 4;
  float* part = (float*)ws; ws += (size_t)32 * NDIM * 4;
  float* S    = (float*)ws; ws += (size_t)NDIM * NDIM * 4;

  convert_bf16<<<4096, 256, 0, stream>>>(Wa, WaB, NDIM * NDIM);
  transpose_convert<<<dim3(32, 32, BDIM), 256, 0, stream>>>(x, curA);
  weff1<<<dim3(8, 16), 256, 0, stream>>>(Wa, Wb, Wc, part);
  weff2<<<8, 256, 0, stream>>>(part, wbe, wce);

  for (int step = 0; step < 2; ++step) {
    const unsigned short* cur = step ? curB : curA;
    t_kernel<<<(BDIM * NDIM) / 4, 256, 0, stream>>>(cur, wbe, wce, bb, bc, t1, t2);
    s_kernel<<<dim3(NDIM / 256, NDIM), 256, 0, stream>>>(t1, t2, S);
    gemm_fused<<<dim3(8, 8, BDIM), 512, 0, stream>>>(
        WaB, cur, t1, t2, S, bias, curB, out, step);
  }
}